// Round 6
// baseline (369.780 us; speedup 1.0000x reference)
//
#include <hip/hip_runtime.h>
#include <hip/hip_bf16.h>
#include <math.h>

#define N_ROWS 16384
#define DIM 128
#define K_CODES 8192
#define EPSF 7e-5f            // top-2 gap flag threshold (split-bf16 err ~1e-5)

// ---- workspace layout (float offsets) --------------------------------------
#define OFF_EN       0u          // eN fp32: 8192*128
#define OFF_ZN       1048576u    // zN fp32: 16384*128
#define OFF_EP       3145728u    // Ep bf16: 8192*384  (p1 prefetch may read ~50KB past end into Zp: harmless)
#define OFF_ZP       4718592u    // Zp bf16: 16384*384
#define OFF_PART     7864320u    // phase1 partials: 4*16384 float4
#define OFF_LINV     8142848u    // 16384
#define OFF_IDX      8159232u    // 16384 int
#define OFF_FLAGLIST 8175616u    // 16384 int
#define OFF_CNT      8192000u    // 8192 u32   <-- memset region starts here
#define OFF_P        8200192u    // 8192 f
#define OFF_MSE      8208384u    // 1
#define OFF_NFLAG    8208385u    // 1 int
#define OFF_REFBUF   8208386u    // 16384 u64
#define MEMSET_BYTES 196616u     // counts + P + mse + nflag + refbuf

typedef __bf16 bf16x8 __attribute__((ext_vector_type(8)));
typedef float  f32x4  __attribute__((ext_vector_type(4)));
#define MFMA16(a, b, c) __builtin_amdgcn_mfma_f32_16x16x32_bf16(a, b, c, 0, 0, 0)

__device__ __forceinline__ void gld_lds16(const ushort* g, ushort* l) {
    __builtin_amdgcn_global_load_lds(
        (const __attribute__((address_space(1))) unsigned int*)g,
        (__attribute__((address_space(3))) unsigned int*)l, 16, 0, 0);
}

__device__ __forceinline__ ushort f2bf(float x) {
    __hip_bfloat16 b = __float2bfloat16(x);
    return *reinterpret_cast<ushort*>(&b);
}
__device__ __forceinline__ float bf2f(ushort u) {
    __hip_bfloat16 b = *reinterpret_cast<__hip_bfloat16*>(&u);
    return __bfloat162float(b);
}

// tiled+swizzled bf16 store: element (tile row r, k) of tile T ->
// chunk = r*8 + ((k>>3 & 7) ^ (r&7)) within kgroup g=k>>6; 16B chunks.
__device__ __forceinline__ void bf_store2(ushort* __restrict__ P, int T, int r,
                                          int rx, int k, ushort e0, ushort e1) {
    int g = k >> 6, kp = (k >> 3) & 7, j = k & 7;
    int off = ((((T * 6 + g) << 10) + (r << 3) + (kp ^ rx)) << 3) + j;
    *reinterpret_cast<ushort2*>(&P[off]) = make_ushort2(e0, e1);
}

// ---- fused prep: normalize z and W, write split-bf16 tiled layouts ---------
// z rows: k-layout [hi | lo | hi];  e rows: [hi | hi | lo]
__global__ __launch_bounds__(256) void k_prep(const float* __restrict__ z,
                                              const float* __restrict__ W,
                                              float* __restrict__ zN,
                                              float* __restrict__ eN,
                                              ushort* __restrict__ Zp,
                                              ushort* __restrict__ Ep) {
    int t = threadIdx.x, w = t >> 6, lane = t & 63;
    int row = blockIdx.x * 4 + w;
    const float* src; float* dstN; ushort* dstP; int mode;
    if (row < N_ROWS) { src = z; dstN = zN; dstP = Zp; mode = 0; }
    else { row -= N_ROWS; src = W; dstN = eN; dstP = Ep; mode = 1; }
    float2 v = *reinterpret_cast<const float2*>(&src[(size_t)row * DIM + lane * 2]);
    float ss = v.x * v.x + v.y * v.y;
#pragma unroll
    for (int off = 32; off; off >>= 1) ss += __shfl_xor(ss, off);
    float nrm = fmaxf(sqrtf(ss), 1e-12f);
    float a = v.x / nrm, b = v.y / nrm;
    *reinterpret_cast<float2*>(&dstN[(size_t)row * DIM + lane * 2]) = make_float2(a, b);
    ushort ha = f2bf(a), hb = f2bf(b);
    ushort la = f2bf(a - bf2f(ha)), lb = f2bf(b - bf2f(hb));
    int T = row >> 7, r = row & 127, rx = r & 7, d = lane * 2;
    bf_store2(dstP, T, r, rx, d, ha, hb);
    if (mode == 0) {
        bf_store2(dstP, T, r, rx, 128 + d, la, lb);
        bf_store2(dstP, T, r, rx, 256 + d, ha, hb);
    } else {
        bf_store2(dstP, T, r, rx, 128 + d, ha, hb);
        bf_store2(dstP, T, r, rx, 256 + d, la, lb);
    }
}

// ---- phase 1: barrier-free MFMA GEMM, all operands direct from global ------
// grid 1024: rg = b>>2 (256 groups of 64 rows), slice = b&3 (2048 codes).
// slice = b&3 is XCD-stationary under b%8 round-robin -> Ep slice L2-resident.
// A frags stationary in registers (Zp groups 4,5 duplicate 0,1 -> 16 frags);
// B frags streamed with a 3-deep rotating register pipeline. No LDS, no syncs.
__global__ __launch_bounds__(256, 2) void k_p1(const ushort* __restrict__ Zp,
                                               const ushort* __restrict__ Ep,
                                               float4* __restrict__ part) {
    int t = threadIdx.x, lane = t & 63, w = t >> 6;
    int rg = blockIdx.x >> 2, slice = blockIdx.x & 3;
    int wm = w >> 1, wn = w & 1;           // 2x2 wave grid over 64 rows x 128 codes
    int n15 = lane & 15, quad = lane >> 4;
    int rx = n15 & 7;
    int T = rg >> 1, half = (rg & 1) << 9;

    // stationary A fragments: [ms][g 0..3][kl]; groups 4,5 map to 0,1
    bf16x8 af[2][4][2];
#pragma unroll
    for (int ms = 0; ms < 2; ++ms) {
        int rchunk = half + ((wm * 32 + ms * 16 + n15) << 3);
#pragma unroll
        for (int g = 0; g < 4; ++g)
#pragma unroll
            for (int kl = 0; kl < 2; ++kl) {
                int kx = (kl * 4 + quad) ^ rx;
                af[ms][g][kl] = *reinterpret_cast<const bf16x8*>(
                    &Zp[(((size_t)(T * 6 + g) << 10) + rchunk + kx) << 3]);
            }
    }

    // per-lane B offsets within one k-group (ushort units)
    int bo[4][2];
#pragma unroll
    for (int ns = 0; ns < 4; ++ns)
#pragma unroll
        for (int kl = 0; kl < 2; ++kl)
            bo[ns][kl] = ((((wn * 64 + ns * 16 + n15) << 3) | ((kl * 4 + quad) ^ rx)) << 3);

    const ushort* eb = Ep + ((size_t)(slice * 96) << 13);  // 16 ctiles x 6 groups x 8192 ushorts

    float sm[8], s2v[8], sl[8];
    unsigned si[8];
#pragma unroll
    for (int s = 0; s < 8; ++s) { sm[s] = -1e30f; s2v[s] = -1e30f; sl[s] = 0.f; si[s] = 0u; }

    // rotating 3-deep B pipeline
    bf16x8 bp[3][4];
#pragma unroll
    for (int j = 0; j < 3; ++j)
#pragma unroll
        for (int ns = 0; ns < 4; ++ns)
            bp[j][ns] = *reinterpret_cast<const bf16x8*>(&eb[((size_t)(j >> 1) << 13) + bo[ns][j & 1]]);

    f32x4 acc[2][4];
#pragma unroll
    for (int i = 0; i < 2; ++i)
#pragma unroll
        for (int j = 0; j < 4; ++j) acc[i][j] = (f32x4)2.0f;

    static const int gmap[6] = {0, 1, 2, 3, 0, 1};

#pragma unroll 12
    for (int xk = 0; xk < 192; ++xk) {
        int s3 = xk % 3, gk = xk % 12;
        bf16x8 bcur[4];
#pragma unroll
        for (int ns = 0; ns < 4; ++ns) bcur[ns] = bp[s3][ns];
        // prefetch xk+3
        const ushort* ep = eb + ((size_t)((xk + 3) >> 1) << 13);
#pragma unroll
        for (int ns = 0; ns < 4; ++ns)
            bp[s3][ns] = *reinterpret_cast<const bf16x8*>(&ep[bo[ns][(xk + 3) & 1]]);
        // 8 MFMA
#pragma unroll
        for (int ms = 0; ms < 2; ++ms)
#pragma unroll
            for (int ns = 0; ns < 4; ++ns)
                acc[ms][ns] = MFMA16(af[ms][gmap[gk >> 1]][gk & 1], bcur[ns], acc[ms][ns]);

        if (gk == 3) {
            // acc = 2 + s_hh (K=128 hi.hi): softmax-denominator snapshot
#pragma unroll
            for (int ms = 0; ms < 2; ++ms)
#pragma unroll
                for (int reg = 0; reg < 4; ++reg) {
                    int s = ms * 4 + reg;
                    float e0 = __expf(fmaf(acc[ms][0][reg], 10.f, -20.f));
                    float e1 = __expf(fmaf(acc[ms][1][reg], 10.f, -20.f));
                    float e2 = __expf(fmaf(acc[ms][2][reg], 10.f, -20.f));
                    float e3 = __expf(fmaf(acc[ms][3][reg], 10.f, -20.f));
                    sl[s] += (e0 + e1) + (e2 + e3);
                }
        }
        if (gk == 11) {
            int ch = xk / 12;
            unsigned cbase = slice * 2048 + ch * 128 + wn * 64 + n15;
#pragma unroll
            for (int ms = 0; ms < 2; ++ms)
#pragma unroll
                for (int reg = 0; reg < 4; ++reg) {
                    int s = ms * 4 + reg;
                    float m = sm[s], m2 = s2v[s];
                    unsigned idx = si[s];
#pragma unroll
                    for (int ns = 0; ns < 4; ++ns) {
                        float v = acc[ms][ns][reg];
                        unsigned code = cbase + ns * 16;
                        float lo = fminf(v, m);
                        m2 = fmaxf(m2, lo);
                        idx = (v > m) ? code : idx;
                        m = fmaxf(v, m);
                    }
                    sm[s] = m; s2v[s] = m2; si[s] = idx;
                }
#pragma unroll
            for (int i = 0; i < 2; ++i)
#pragma unroll
                for (int j = 0; j < 4; ++j) acc[i][j] = (f32x4)2.0f;
        }
    }

    // cross-lane merge over the 16-lane col group
#pragma unroll
    for (int ms = 0; ms < 2; ++ms)
#pragma unroll
        for (int reg = 0; reg < 4; ++reg) {
            int s = ms * 4 + reg;
            float m = sm[s], m2 = s2v[s], l = sl[s];
            unsigned idx = si[s];
#pragma unroll
            for (int off = 1; off < 16; off <<= 1) {
                float om  = __shfl_xor(m, off);
                float om2 = __shfl_xor(m2, off);
                float ol  = __shfl_xor(l, off);
                unsigned oi = (unsigned)__shfl_xor((int)idx, off);
                m2 = fmaxf(fmaxf(m2, om2), fminf(m, om));
                l += ol;
                bool take = (om > m) || (om == m && oi < idx);
                idx = take ? oi : idx;
                m = fmaxf(m, om);
            }
            if (n15 == 0) {
                int row = rg * 64 + wm * 32 + ms * 16 + quad * 4 + reg;
                part[slice * N_ROWS + row] = make_float4(m, l, __uint_as_float(idx), m2);
            }
        }
}

// ---- merge 4 slice-partials per row; counts; flag tiny top-2 gap -----------
__global__ __launch_bounds__(256) void k_merge(const float4* __restrict__ part,
                                               float* __restrict__ linv_out,
                                               int* __restrict__ idx_out,
                                               unsigned int* __restrict__ counts,
                                               int* __restrict__ flaglist,
                                               int* __restrict__ nflag) {
    int row = blockIdx.x * 256 + threadIdx.x;
    float m = -1e30f, m2 = -1e30f, l = 0.f;
    unsigned idx = 0u;
#pragma unroll
    for (int s = 0; s < 4; ++s) {
        float4 p = part[s * N_ROWS + row];
        float om = p.x, ol = p.y, om2 = p.w;
        unsigned oi = __float_as_uint(p.z);
        m2 = fmaxf(fmaxf(m2, om2), fminf(m, om));
        l += ol;
        bool take = (om > m) || (om == m && oi < idx);
        idx = take ? oi : idx;
        m = fmaxf(m, om);
    }
    linv_out[row] = 1.0f / l;
    idx_out[row] = (int)idx;
    atomicAdd(&counts[idx], 1u);
    if (m - m2 < EPSF) {
        int pos = atomicAdd(nflag, 1);
        flaglist[pos] = row;
    }
}

// ---- fp64 exact re-argmax for flagged rows ---------------------------------
__global__ __launch_bounds__(256) void k_refine(const float* __restrict__ zN,
                                                const float* __restrict__ eN,
                                                const int* __restrict__ flaglist,
                                                const int* __restrict__ nflag,
                                                unsigned long long* __restrict__ refbuf) {
    int nf = *nflag;
    if (nf > N_ROWS) nf = N_ROWS;
    int csl = blockIdx.x & 7;
    int t = threadIdx.x;
    __shared__ float zl[DIM];
    for (int fi = blockIdx.x >> 3; fi < nf; fi += 512) {
        int row = flaglist[fi];
        __syncthreads();
        if (t < DIM) zl[t] = zN[(size_t)row * DIM + t];
        __syncthreads();
        double best = -1e300;
        int bc = 0x7FFFFFFF;
#pragma unroll
        for (int j = 0; j < 4; ++j) {
            int c = csl * 1024 + j * 256 + t;
            const float* e = &eN[(size_t)c * DIM];
            double s = 0.0;
#pragma unroll 8
            for (int d = 0; d < DIM; ++d) s += (double)zl[d] * (double)e[d];
            if (s > best) { best = s; bc = c; }
        }
#pragma unroll
        for (int off = 1; off < 64; off <<= 1) {
            double ob = __shfl_xor(best, off);
            int oc = __shfl_xor(bc, off);
            if (ob > best || (ob == best && oc < bc)) { best = ob; bc = oc; }
        }
        if ((t & 63) == 0) {
            unsigned long long u = (unsigned long long)__double_as_longlong(best);
            u = (u & 0x8000000000000000ull) ? ~u : (u | 0x8000000000000000ull);
            unsigned long long key = (u & ~0x1FFFull) | (unsigned long long)(8191 - bc);
            atomicMax(&refbuf[row], key);
        }
    }
}

__global__ __launch_bounds__(256) void k_fixidx(const int* __restrict__ flaglist,
                                                const int* __restrict__ nflag,
                                                const unsigned long long* __restrict__ refbuf,
                                                int* __restrict__ idx,
                                                unsigned int* __restrict__ counts) {
    int i = blockIdx.x * 256 + threadIdx.x;
    int nf = *nflag;
    if (nf > N_ROWS) nf = N_ROWS;
    if (i < nf) {
        int row = flaglist[i];
        int newi = 8191 - (int)(refbuf[row] & 0x1FFFull);
        int oldi = idx[row];
        if (newi != oldi) {
            idx[row] = newi;
            atomicAdd(&counts[oldi], 0xFFFFFFFFu);
            atomicAdd(&counts[newi], 1u);
        }
    }
}

// ---- phase 2: K=128 (hi.hi) GEMM, codes resident in LDS --------------------
__global__ __launch_bounds__(256, 3) void k_p2(const ushort* __restrict__ Zp,
                                               const ushort* __restrict__ Ep,
                                               const float* __restrict__ linv_in,
                                               float* __restrict__ P_sum) {
    __shared__ ushort Ac[16384];  // 32KB: 128 codes x 128 k (g0,g1)
    __shared__ ushort Bu[8192];   // 16KB: 128 rows x 64 k
    int t = threadIdx.x, lane = t & 63, w = t >> 6;
    int cg = blockIdx.x >> 4, rs = blockIdx.x & 15;
    int wm = w >> 1, wn = w & 1;
    int n15 = lane & 15, quad = lane >> 4;
    int rx = n15 & 7;

#pragma unroll
    for (int it = 0; it < 8; ++it) {
        int chunk = it * 256 + t;
        gld_lds16(Ep + ((((size_t)cg * 6 << 10) + chunk) << 3), &Ac[chunk << 3]);
    }

    int aoff[4], boff[4];
#pragma unroll
    for (int ms = 0; ms < 4; ++ms) aoff[ms] = (wm * 64 + ms * 16 + n15) << 3;
#pragma unroll
    for (int ns = 0; ns < 4; ++ns) boff[ns] = (wn * 64 + ns * 16 + n15) << 3;

    float pacc[16];
#pragma unroll
    for (int s = 0; s < 16; ++s) pacc[s] = 0.f;

    for (int ch = 0; ch < 8; ++ch) {
        int rtile = rs * 8 + ch;
        f32x4 acc[4][4];
#pragma unroll
        for (int i = 0; i < 4; ++i)
#pragma unroll
            for (int j = 0; j < 4; ++j) acc[i][j] = (f32x4)2.0f;

#pragma unroll
        for (int g = 0; g < 2; ++g) {
            __syncthreads();
            const ushort* gb = Zp + (((size_t)rtile * 6 + g) << 13);
#pragma unroll
            for (int rr = 0; rr < 4; ++rr) {
                int q = (rr * 256 + t) << 3;
                gld_lds16(gb + q, &Bu[q]);
            }
            __syncthreads();
            int gbase = g << 10;
#pragma unroll
            for (int kl = 0; kl < 2; ++kl) {
                int kx = (kl * 4 + quad) ^ rx;
                bf16x8 af[4], bfr[4];
#pragma unroll
                for (int ms = 0; ms < 4; ++ms)
                    af[ms] = *reinterpret_cast<const bf16x8*>(&Ac[(gbase + aoff[ms] + kx) << 3]);
#pragma unroll
                for (int ns = 0; ns < 4; ++ns)
                    bfr[ns] = *reinterpret_cast<const bf16x8*>(&Bu[(boff[ns] + kx) << 3]);
#pragma unroll
                for (int ms = 0; ms < 4; ++ms)
#pragma unroll
                    for (int ns = 0; ns < 4; ++ns)
                        acc[ms][ns] = MFMA16(af[ms], bfr[ns], acc[ms][ns]);
            }
        }
        int rbase = rtile * 128 + wn * 64 + n15;
        float li[4];
#pragma unroll
        for (int ns = 0; ns < 4; ++ns) li[ns] = linv_in[rbase + ns * 16];
#pragma unroll
        for (int ms = 0; ms < 4; ++ms)
#pragma unroll
            for (int reg = 0; reg < 4; ++reg) {
                int s = ms * 4 + reg;
                float p = pacc[s];
#pragma unroll
                for (int ns = 0; ns < 4; ++ns)
                    p = fmaf(__expf(fmaf(acc[ms][ns][reg], 10.f, -20.f)), li[ns], p);
                pacc[s] = p;
            }
    }
#pragma unroll
    for (int s = 0; s < 16; ++s) {
#pragma unroll
        for (int off = 1; off < 16; off <<= 1) pacc[s] += __shfl_xor(pacc[s], off);
    }
    if (n15 == 0) {
#pragma unroll
        for (int ms = 0; ms < 4; ++ms)
#pragma unroll
            for (int reg = 0; reg < 4; ++reg)
                atomicAdd(&P_sum[cg * 128 + wm * 64 + ms * 16 + quad * 4 + reg],
                          pacc[ms * 4 + reg]);
    }
}

// ---- gather z_q_st + commit-loss partial -----------------------------------
__global__ __launch_bounds__(256) void k_gather(const float* __restrict__ z,
                                                const float* __restrict__ W,
                                                const int* __restrict__ idx,
                                                float* __restrict__ out,
                                                float* __restrict__ mse) {
    int v = blockIdx.x * 256 + threadIdx.x;
    int row = v >> 5;
    int id = idx[row];
    float4 q = *reinterpret_cast<const float4*>(&W[(size_t)id * DIM + (v & 31) * 4]);
    float4 zz = *reinterpret_cast<const float4*>(&z[(size_t)v * 4]);
    float dx = q.x - zz.x, dy = q.y - zz.y, dz = q.z - zz.z, dw = q.w - zz.w;
    *reinterpret_cast<float4*>(&out[(size_t)v * 4]) = q;
    float e = dx * dx + dy * dy + dz * dz + dw * dw;
#pragma unroll
    for (int off = 1; off < 64; off <<= 1) e += __shfl_xor(e, off);
    __shared__ float red[4];
    int lane = threadIdx.x & 63, wv = threadIdx.x >> 6;
    if (lane == 0) red[wv] = e;
    __syncthreads();
    if (threadIdx.x == 0) atomicAdd(mse, red[0] + red[1] + red[2] + red[3]);
}

// ---- finalize scalars -------------------------------------------------------
__global__ __launch_bounds__(256) void k_finalize(const unsigned int* __restrict__ counts,
                                                  const float* __restrict__ P_sum,
                                                  const float* __restrict__ mse,
                                                  float* __restrict__ out) {
    int t = threadIdx.x;
    float s1 = 0.f, s2 = 0.f;
    for (int k = t; k < K_CODES; k += 256) {
        float em = (float)counts[k] * (1.0f / 16384.0f);
        s1 += em * logf(em + 1e-8f);
        float p = P_sum[k] * (1.0f / 16384.0f) + 1e-8f;
        s2 += p * logf(p);
    }
#pragma unroll
    for (int off = 1; off < 64; off <<= 1) {
        s1 += __shfl_xor(s1, off);
        s2 += __shfl_xor(s2, off);
    }
    __shared__ float r1[4], r2[4];
    int lane = t & 63, wv = t >> 6;
    if (lane == 0) { r1[wv] = s1; r2[wv] = s2; }
    __syncthreads();
    if (t == 0) {
        float S1 = r1[0] + r1[1] + r1[2] + r1[3];
        float S2 = r2[0] + r2[1] + r2[2] + r2[3];
        out[2097152] = 1.25f * mse[0] * (1.0f / 2097152.0f);
        out[2097153] = expf(-S1);
        out[2097154] = -S2;
    }
}

extern "C" void kernel_launch(void* const* d_in, const int* in_sizes, int n_in,
                              void* d_out, int out_size, void* d_ws, size_t ws_size,
                              hipStream_t stream) {
    (void)in_sizes; (void)n_in; (void)out_size; (void)ws_size;
    const float* z = (const float*)d_in[0];
    const float* W = (const float*)d_in[1];
    float* ws = (float*)d_ws;
    float* eN = ws + OFF_EN;
    float* zN = ws + OFF_ZN;
    ushort* Ep = (ushort*)(ws + OFF_EP);
    ushort* Zp = (ushort*)(ws + OFF_ZP);
    float4* part = (float4*)(ws + OFF_PART);
    float* linv = ws + OFF_LINV;
    int* idx = (int*)(ws + OFF_IDX);
    int* flaglist = (int*)(ws + OFF_FLAGLIST);
    unsigned int* counts = (unsigned int*)(ws + OFF_CNT);
    float* P = ws + OFF_P;
    float* mse = ws + OFF_MSE;
    int* nflag = (int*)(ws + OFF_NFLAG);
    unsigned long long* refbuf = (unsigned long long*)(ws + OFF_REFBUF);
    float* out = (float*)d_out;

    hipMemsetAsync(ws + OFF_CNT, 0, MEMSET_BYTES, stream);
    k_prep<<<(N_ROWS + K_CODES) / 4, 256, 0, stream>>>(z, W, zN, eN, Zp, Ep);
    k_p1<<<1024, 256, 0, stream>>>(Zp, Ep, part);
    k_merge<<<N_ROWS / 256, 256, 0, stream>>>(part, linv, idx, counts, flaglist, nflag);
    k_refine<<<4096, 256, 0, stream>>>(zN, eN, flaglist, nflag, refbuf);
    k_fixidx<<<64, 256, 0, stream>>>(flaglist, nflag, refbuf, idx, counts);
    k_p2<<<1024, 256, 0, stream>>>(Zp, Ep, linv, P);
    k_gather<<<(N_ROWS * DIM / 4) / 256, 256, 0, stream>>>(z, W, idx, out, mse);
    k_finalize<<<1, 256, 0, stream>>>(counts, P, mse, out);
}

// Round 7
// 332.762 us; speedup vs baseline: 1.1112x; 1.1112x over previous
//
#include <hip/hip_runtime.h>
#include <hip/hip_bf16.h>
#include <math.h>

#define N_ROWS 16384
#define DIM 128
#define K_CODES 8192
#define EPS2 2e-3f            // hh-gap flag threshold (fp32-vs-hh delta rms ~1.4e-4)
#define EPSF 7e-5f            // split-gap flag threshold (split err ~1e-5)

// ---- workspace layout (float offsets) --------------------------------------
#define OFF_EN       0u          // eN fp32: 8192*128 = 1,048,576
#define OFF_ZN       1048576u    // zN fp32: 16384*128
#define OFF_EP       3145728u    // Ep bf16 4-group [hi|lo]: 64 tiles * 32768 us = 1,048,576 f
#define OFF_ZP       4194304u    // Zp bf16 4-group: 128 tiles * 32768 us = 2,097,152 f
#define OFF_ZC       6291456u    // Zc compact: 128 tiles(64r) * 16384 us = 1,048,576 f
#define OFF_PART     7340032u    // p1 partials: 4*16384 float4 = 262,144 f
#define OFF_PART2    7602176u    // s2 partials: 8*8192 float4 = 262,144 f
#define OFF_LINV     7864320u    // 16384
#define OFF_IDX      7880704u    // 16384 int
#define OFF_FLA      7897088u    // 16384 int
#define OFF_FLB      7913472u    // 16384 int
#define OFF_CNT      7929856u    // 8192 u32   <-- memset region starts here
#define OFF_P        7938048u    // 8192 f
#define OFF_MSE      7946240u    // 1
#define OFF_NFA      7946241u    // 1 int
#define OFF_NFB      7946242u    // 1 int (+1 pad)
#define OFF_REFBUF   7946244u    // 16384 u64 (byte off %8 == 0)
#define MEMSET_BYTES 196624u

typedef __bf16 bf16x8 __attribute__((ext_vector_type(8)));
typedef float  f32x4  __attribute__((ext_vector_type(4)));
#define MFMA16(a, b, c) __builtin_amdgcn_mfma_f32_16x16x32_bf16(a, b, c, 0, 0, 0)

__device__ __forceinline__ void gld_lds16(const ushort* g, ushort* l) {
    __builtin_amdgcn_global_load_lds(
        (const __attribute__((address_space(1))) unsigned int*)g,
        (__attribute__((address_space(3))) unsigned int*)l, 16, 0, 0);
}

__device__ __forceinline__ ushort f2bf(float x) {
    __hip_bfloat16 b = __float2bfloat16(x);
    return *reinterpret_cast<ushort*>(&b);
}
__device__ __forceinline__ float bf2f(ushort u) {
    __hip_bfloat16 b = *reinterpret_cast<__hip_bfloat16*>(&u);
    return __bfloat162float(b);
}

// 4-group tiled+swizzled store: tile T (128 rows), row r, k in [0,256):
// g = k>>6, chunk = r*8 + ((k>>3 & 7) ^ (r&7)); 16B chunks.
__device__ __forceinline__ void bf_store2(ushort* __restrict__ P, int T, int r,
                                          int rx, int k, ushort e0, ushort e1) {
    int g = k >> 6, kp = (k >> 3) & 7, j = k & 7;
    int off = (((((T << 2) + g) << 10) + (r << 3) + (kp ^ rx)) << 3) + j;
    *reinterpret_cast<ushort2*>(&P[off]) = make_ushort2(e0, e1);
}

// ---- fused prep: normalize z and W; write fp32 + 4-group [hi|lo] bf16 ------
__global__ __launch_bounds__(256) void k_prep(const float* __restrict__ z,
                                              const float* __restrict__ W,
                                              float* __restrict__ zN,
                                              float* __restrict__ eN,
                                              ushort* __restrict__ Zp,
                                              ushort* __restrict__ Ep) {
    int t = threadIdx.x, w = t >> 6, lane = t & 63;
    int row = blockIdx.x * 4 + w;
    const float* src; float* dstN; ushort* dstP;
    if (row < N_ROWS) { src = z; dstN = zN; dstP = Zp; }
    else { row -= N_ROWS; src = W; dstN = eN; dstP = Ep; }
    float2 v = *reinterpret_cast<const float2*>(&src[(size_t)row * DIM + lane * 2]);
    float ss = v.x * v.x + v.y * v.y;
#pragma unroll
    for (int off = 32; off; off >>= 1) ss += __shfl_xor(ss, off);
    float nrm = fmaxf(sqrtf(ss), 1e-12f);
    float a = v.x / nrm, b = v.y / nrm;
    *reinterpret_cast<float2*>(&dstN[(size_t)row * DIM + lane * 2]) = make_float2(a, b);
    ushort ha = f2bf(a), hb = f2bf(b);
    ushort la = f2bf(a - bf2f(ha)), lb = f2bf(b - bf2f(hb));
    int T = row >> 7, r = row & 127, rx = r & 7, d = lane * 2;
    bf_store2(dstP, T, r, rx, d, ha, hb);        // hi -> groups 0,1
    bf_store2(dstP, T, r, rx, 128 + d, la, lb);  // lo -> groups 2,3
}

// ---- phase 1: hh K=128 GEMM; A reg-stationary; B dbuf-LDS, 1 barrier/ch ----
// grid 1024: rg = b>>2 (256 groups of 64 rows), slice = b&3 (2048 codes).
__global__ __launch_bounds__(256, 2) void k_p1(const ushort* __restrict__ Zp,
                                               const ushort* __restrict__ Ep,
                                               float4* __restrict__ part) {
    __shared__ ushort Bu[2][16384];  // 2 x 32KB: 128 codes x 128 K (hi)
    int t = threadIdx.x, lane = t & 63, w = t >> 6;
    int rg = blockIdx.x >> 2, slice = blockIdx.x & 3;
    int wm = w >> 1, wn = w & 1;
    int n15 = lane & 15, quad = lane >> 4;
    int T = rg >> 1, rofs = (rg & 1) << 6;

    // stationary A: 8 frags (64 rows per block; 32 per wave)
    bf16x8 af[2][2][2];  // [ms][g][kl]
#pragma unroll
    for (int ms = 0; ms < 2; ++ms) {
        int r = rofs + wm * 32 + ms * 16 + n15, rx = r & 7;
#pragma unroll
        for (int g = 0; g < 2; ++g)
#pragma unroll
            for (int kl = 0; kl < 2; ++kl)
                af[ms][g][kl] = *reinterpret_cast<const bf16x8*>(
                    &Zp[(((((T << 2) + g) << 10) + (r << 3) + (((kl * 4 + quad)) ^ rx)) << 3)]);
    }

    float sm[8], s2v[8], sl[8];
    unsigned si[8];
#pragma unroll
    for (int s = 0; s < 8; ++s) { sm[s] = -1e30f; s2v[s] = -1e30f; sl[s] = 0.f; si[s] = 0u; }

    // pre-stage ch 0
    {
        const ushort* gb = Ep + (((size_t)(slice * 16) << 2) << 13);
#pragma unroll
        for (int it = 0; it < 8; ++it) {
            int cpos = it * 256 + t;
            gld_lds16(gb + (cpos << 3), &Bu[0][cpos << 3]);
        }
    }
    int bufc = 0;
    for (int ch = 0; ch < 16; ++ch) {
        __syncthreads();
        if (ch < 15) {
            const ushort* gb = Ep + (((size_t)((slice * 16 + ch + 1) << 2)) << 13);
            ushort* dst = Bu[bufc ^ 1];
#pragma unroll
            for (int it = 0; it < 8; ++it) {
                int cpos = it * 256 + t;
                gld_lds16(gb + (cpos << 3), &dst[cpos << 3]);
            }
        }
        const ushort* bsrc = Bu[bufc];
        f32x4 acc[2][4];
#pragma unroll
        for (int i = 0; i < 2; ++i)
#pragma unroll
            for (int j = 0; j < 4; ++j) acc[i][j] = (f32x4)2.0f;
#pragma unroll
        for (int g = 0; g < 2; ++g)
#pragma unroll
            for (int kl = 0; kl < 2; ++kl) {
                bf16x8 bfr[4];
#pragma unroll
                for (int ns = 0; ns < 4; ++ns) {
                    int c = wn * 64 + ns * 16 + n15;
                    int kx = (kl * 4 + quad) ^ (c & 7);
                    bfr[ns] = *reinterpret_cast<const bf16x8*>(
                        &bsrc[(((g << 10) + (c << 3) + kx) << 3)]);
                }
#pragma unroll
                for (int ms = 0; ms < 2; ++ms)
#pragma unroll
                    for (int ns = 0; ns < 4; ++ns)
                        acc[ms][ns] = MFMA16(af[ms][g][kl], bfr[ns], acc[ms][ns]);
            }
        // epilogue: sl + (m, m2, idx) on hh scores (biased +2)
        unsigned cbase = (unsigned)((slice * 16 + ch) * 128 + wn * 64 + n15);
#pragma unroll
        for (int ms = 0; ms < 2; ++ms)
#pragma unroll
            for (int reg = 0; reg < 4; ++reg) {
                int s = ms * 4 + reg;
                float m = sm[s], m2 = s2v[s], l = 0.f;
                unsigned idx = si[s];
#pragma unroll
                for (int ns = 0; ns < 4; ++ns) {
                    float v = acc[ms][ns][reg];
                    l += __expf(fmaf(v, 10.f, -20.f));
                    float lo = fminf(v, m);
                    m2 = fmaxf(m2, lo);
                    idx = (v > m) ? (cbase + ns * 16) : idx;
                    m = fmaxf(v, m);
                }
                sl[s] += l; sm[s] = m; s2v[s] = m2; si[s] = idx;
            }
        bufc ^= 1;
    }
    // cross-lane merge over 16-lane col group
#pragma unroll
    for (int ms = 0; ms < 2; ++ms)
#pragma unroll
        for (int reg = 0; reg < 4; ++reg) {
            int s = ms * 4 + reg;
            float m = sm[s], m2 = s2v[s], l = sl[s];
            unsigned idx = si[s];
#pragma unroll
            for (int off = 1; off < 16; off <<= 1) {
                float om  = __shfl_xor(m, off);
                float om2 = __shfl_xor(m2, off);
                float ol  = __shfl_xor(l, off);
                unsigned oi = (unsigned)__shfl_xor((int)idx, off);
                m2 = fmaxf(fmaxf(m2, om2), fminf(m, om));
                l += ol;
                bool take = (om > m) || (om == m && oi < idx);
                idx = take ? oi : idx;
                m = fmaxf(m, om);
            }
            if (n15 == 0) {
                int row = rg * 64 + wm * 32 + ms * 16 + quad * 4 + reg;
                part[slice * N_ROWS + row] = make_float4(m, l, __uint_as_float(idx), m2);
            }
        }
}

// ---- merge 4 slice-partials; counts; flag hh-gap < EPS2 --------------------
__global__ __launch_bounds__(256) void k_merge(const float4* __restrict__ part,
                                               float* __restrict__ linv_out,
                                               int* __restrict__ idx_out,
                                               unsigned int* __restrict__ counts,
                                               int* __restrict__ flaglistA,
                                               int* __restrict__ nfA) {
    int row = blockIdx.x * 256 + threadIdx.x;
    float m = -1e30f, m2 = -1e30f, l = 0.f;
    unsigned idx = 0u;
#pragma unroll
    for (int s = 0; s < 4; ++s) {
        float4 p = part[s * N_ROWS + row];
        float om = p.x, ol = p.y, om2 = p.w;
        unsigned oi = __float_as_uint(p.z);
        m2 = fmaxf(fmaxf(m2, om2), fminf(m, om));
        l += ol;
        bool take = (om > m) || (om == m && oi < idx);
        idx = take ? oi : idx;
        m = fmaxf(m, om);
    }
    linv_out[row] = 1.0f / l;
    idx_out[row] = (int)idx;
    atomicAdd(&counts[idx], 1u);
    if (m - m2 < EPS2) {
        int pos = atomicAdd(nfA, 1);
        if (pos < 8192) flaglistA[pos] = row;
    }
}

// ---- gather flagged rows into compact split-K tiles (64-row tiles) ---------
__global__ __launch_bounds__(256) void k_gather2(const ushort* __restrict__ Zp,
                                                 const int* __restrict__ flaglistA,
                                                 const int* __restrict__ nfA,
                                                 ushort* __restrict__ Zc) {
    int nf2 = *nfA; if (nf2 > 8192) nf2 = 8192;
    int total = nf2 * 32;  // 4 groups x 8 chunks per row
    const uint4* srcv = reinterpret_cast<const uint4*>(Zp);
    uint4* dstv = reinterpret_cast<uint4*>(Zc);
    for (int c = blockIdx.x * 256 + threadIdx.x; c < total; c += 65536) {
        int crow = c >> 5, g = (c >> 3) & 3, kp = c & 7;
        int row = flaglistA[crow];
        int Ts = row >> 7, rs = row & 127;
        int sidx = (((Ts << 2) + g) << 10) + (rs << 3) + (kp ^ (rs & 7));
        int Td = crow >> 6, rd = crow & 63;
        int didx = (((Td << 2) + g) << 9) + (rd << 3) + (kp ^ (rd & 7));
        dstv[didx] = srcv[sidx];
    }
}

// ---- stage 2: split-K re-argmax for flagged rows (barrier-free, E-dedup) ---
// grid 1024: cg2 = b>>3 (compact rowgroup of 64), csl = b&7 (1024 codes).
__global__ __launch_bounds__(256, 1) void k_s2(const ushort* __restrict__ Zc,
                                               const ushort* __restrict__ Ep,
                                               const int* __restrict__ nfA,
                                               float4* __restrict__ part2) {
    int nf2 = *nfA; if (nf2 > 8192) nf2 = 8192;
    int cg2 = blockIdx.x >> 3, csl = blockIdx.x & 7;
    if (cg2 * 64 >= nf2) return;
    int t = threadIdx.x, lane = t & 63, w = t >> 6;
    int wm = w >> 1, wn = w & 1;
    int n15 = lane & 15, quad = lane >> 4;

    // stationary A: 16 frags [ms][gz 0..3][kl]
    bf16x8 af[2][4][2];
#pragma unroll
    for (int ms = 0; ms < 2; ++ms) {
        int r = wm * 32 + ms * 16 + n15, rx = r & 7;
#pragma unroll
        for (int gz = 0; gz < 4; ++gz)
#pragma unroll
            for (int kl = 0; kl < 2; ++kl)
                af[ms][gz][kl] = *reinterpret_cast<const bf16x8*>(
                    &Zc[(((((cg2 << 2) + gz) << 9) + (r << 3) + ((kl * 4 + quad) ^ rx)) << 3)]);
    }

    int bo[4][2];
#pragma unroll
    for (int ns = 0; ns < 4; ++ns)
#pragma unroll
        for (int kl = 0; kl < 2; ++kl) {
            int c = wn * 64 + ns * 16 + n15;
            bo[ns][kl] = (((c << 3) | ((kl * 4 + quad) ^ (c & 7))) << 3);
        }

    float sm[8], s2v[8];
    unsigned si[8];
#pragma unroll
    for (int s = 0; s < 8; ++s) { sm[s] = -1e30f; s2v[s] = -1e30f; si[s] = 0u; }

    // B step gs = ch*8 + (ge*2 + kl); base tile = csl*8 + ch
    bf16x8 bp[3][4];
#pragma unroll
    for (int j = 0; j < 3; ++j) {
        const ushort* gb = Ep + (((size_t)(((csl * 8 + (j >> 3)) << 2) + ((j >> 1) & 3))) << 13);
#pragma unroll
        for (int ns = 0; ns < 4; ++ns)
            bp[j][ns] = *reinterpret_cast<const bf16x8*>(&gb[bo[ns][j & 1]]);
    }

    f32x4 acc[2][4];
#pragma unroll
    for (int i = 0; i < 2; ++i)
#pragma unroll
        for (int j = 0; j < 4; ++j) acc[i][j] = (f32x4)2.0f;

#pragma unroll 8
    for (int gs = 0; gs < 64; ++gs) {
        int s3 = gs % 3, kl = gs & 1, ge = (gs >> 1) & 3;
        bf16x8 bcur[4];
#pragma unroll
        for (int ns = 0; ns < 4; ++ns) bcur[ns] = bp[s3][ns];
        // prefetch gs+3
        {
            int gn = gs + 3;
            const ushort* gb = Ep + (((size_t)(((csl * 8 + (gn >> 3)) << 2) + ((gn >> 1) & 3))) << 13);
#pragma unroll
            for (int ns = 0; ns < 4; ++ns)
                bp[s3][ns] = *reinterpret_cast<const bf16x8*>(&gb[bo[ns][gn & 1]]);
        }
        // MFMA: ge 0 -> A{0,2}; ge 1 -> A{1,3}; ge 2 -> A{0}; ge 3 -> A{1}
        int a0 = ge & 1, a1 = (ge & 1) + 2;
        bool two = (ge < 2);
#pragma unroll
        for (int ms = 0; ms < 2; ++ms)
#pragma unroll
            for (int ns = 0; ns < 4; ++ns)
                acc[ms][ns] = MFMA16(af[ms][a0][kl], bcur[ns], acc[ms][ns]);
        if (two) {
#pragma unroll
            for (int ms = 0; ms < 2; ++ms)
#pragma unroll
                for (int ns = 0; ns < 4; ++ns)
                    acc[ms][ns] = MFMA16(af[ms][a1][kl], bcur[ns], acc[ms][ns]);
        }
        if ((gs & 7) == 7) {
            int ch = gs >> 3;
            unsigned cbase = (unsigned)((csl * 8 + ch) * 128 + wn * 64 + n15);
#pragma unroll
            for (int ms = 0; ms < 2; ++ms)
#pragma unroll
                for (int reg = 0; reg < 4; ++reg) {
                    int s = ms * 4 + reg;
                    float m = sm[s], m2 = s2v[s];
                    unsigned idx = si[s];
#pragma unroll
                    for (int ns = 0; ns < 4; ++ns) {
                        float v = acc[ms][ns][reg];
                        float lo = fminf(v, m);
                        m2 = fmaxf(m2, lo);
                        idx = (v > m) ? (cbase + ns * 16) : idx;
                        m = fmaxf(v, m);
                    }
                    sm[s] = m; s2v[s] = m2; si[s] = idx;
                }
#pragma unroll
            for (int i = 0; i < 2; ++i)
#pragma unroll
                for (int j = 0; j < 4; ++j) acc[i][j] = (f32x4)2.0f;
        }
    }
#pragma unroll
    for (int ms = 0; ms < 2; ++ms)
#pragma unroll
        for (int reg = 0; reg < 4; ++reg) {
            int s = ms * 4 + reg;
            float m = sm[s], m2 = s2v[s];
            unsigned idx = si[s];
#pragma unroll
            for (int off = 1; off < 16; off <<= 1) {
                float om  = __shfl_xor(m, off);
                float om2 = __shfl_xor(m2, off);
                unsigned oi = (unsigned)__shfl_xor((int)idx, off);
                m2 = fmaxf(fmaxf(m2, om2), fminf(m, om));
                bool take = (om > m) || (om == m && oi < idx);
                idx = take ? oi : idx;
                m = fmaxf(m, om);
            }
            if (n15 == 0) {
                int crow = cg2 * 64 + wm * 32 + ms * 16 + quad * 4 + reg;
                part2[csl * 8192 + crow] = make_float4(m, 0.f, __uint_as_float(idx), m2);
            }
        }
}

// ---- merge stage-2 slices; fix idx/counts; flag split-gap < EPSF -----------
__global__ __launch_bounds__(256) void k_merge2(const float4* __restrict__ part2,
                                                const int* __restrict__ flaglistA,
                                                const int* __restrict__ nfA,
                                                int* __restrict__ idx_arr,
                                                unsigned int* __restrict__ counts,
                                                int* __restrict__ flaglistB,
                                                int* __restrict__ nfB) {
    int i = blockIdx.x * 256 + threadIdx.x;
    int nf2 = *nfA; if (nf2 > 8192) nf2 = 8192;
    if (i >= nf2) return;
    int row = flaglistA[i];
    float m = -1e30f, m2 = -1e30f;
    unsigned idx = 0u;
#pragma unroll
    for (int s = 0; s < 8; ++s) {
        float4 p = part2[s * 8192 + i];
        float om = p.x, om2 = p.w;
        unsigned oi = __float_as_uint(p.z);
        m2 = fmaxf(fmaxf(m2, om2), fminf(m, om));
        bool take = (om > m) || (om == m && oi < idx);
        idx = take ? oi : idx;
        m = fmaxf(m, om);
    }
    int newi = (int)idx, oldi = idx_arr[row];
    if (newi != oldi) {
        idx_arr[row] = newi;
        atomicAdd(&counts[oldi], 0xFFFFFFFFu);
        atomicAdd(&counts[newi], 1u);
    }
    if (m - m2 < EPSF) {
        int pos = atomicAdd(nfB, 1);
        if (pos < N_ROWS) flaglistB[pos] = row;
    }
}

// ---- fp64 exact re-argmax for stage-3 rows ---------------------------------
__global__ __launch_bounds__(256) void k_refine(const float* __restrict__ zN,
                                                const float* __restrict__ eN,
                                                const int* __restrict__ flaglistB,
                                                const int* __restrict__ nfB,
                                                unsigned long long* __restrict__ refbuf) {
    int nf = *nfB;
    if (nf > N_ROWS) nf = N_ROWS;
    int csl = blockIdx.x & 7;
    int t = threadIdx.x;
    __shared__ float zl[DIM];
    for (int fi = blockIdx.x >> 3; fi < nf; fi += 512) {
        int row = flaglistB[fi];
        __syncthreads();
        if (t < DIM) zl[t] = zN[(size_t)row * DIM + t];
        __syncthreads();
        double best = -1e300;
        int bc = 0x7FFFFFFF;
#pragma unroll
        for (int j = 0; j < 4; ++j) {
            int c = csl * 1024 + j * 256 + t;
            const float* e = &eN[(size_t)c * DIM];
            double s = 0.0;
#pragma unroll 8
            for (int d = 0; d < DIM; ++d) s += (double)zl[d] * (double)e[d];
            if (s > best) { best = s; bc = c; }
        }
#pragma unroll
        for (int off = 1; off < 64; off <<= 1) {
            double ob = __shfl_xor(best, off);
            int oc = __shfl_xor(bc, off);
            if (ob > best || (ob == best && oc < bc)) { best = ob; bc = oc; }
        }
        if ((t & 63) == 0) {
            unsigned long long u = (unsigned long long)__double_as_longlong(best);
            u = (u & 0x8000000000000000ull) ? ~u : (u | 0x8000000000000000ull);
            unsigned long long key = (u & ~0x1FFFull) | (unsigned long long)(8191 - bc);
            atomicMax(&refbuf[row], key);
        }
    }
}

__global__ __launch_bounds__(256) void k_fixidx(const int* __restrict__ flaglistB,
                                                const int* __restrict__ nfB,
                                                const unsigned long long* __restrict__ refbuf,
                                                int* __restrict__ idx,
                                                unsigned int* __restrict__ counts) {
    int i = blockIdx.x * 256 + threadIdx.x;
    int nf = *nfB;
    if (nf > N_ROWS) nf = N_ROWS;
    if (i < nf) {
        int row = flaglistB[i];
        int newi = 8191 - (int)(refbuf[row] & 0x1FFFull);
        int oldi = idx[row];
        if (newi != oldi) {
            idx[row] = newi;
            atomicAdd(&counts[oldi], 0xFFFFFFFFu);
            atomicAdd(&counts[newi], 1u);
        }
    }
}

// ---- phase 2: mirrored p1 — codes reg-stationary, rows dbuf-LDS ------------
// grid 512: cg = b>>2 (128 groups of 64 codes), rslice = b&3 (4096 rows).
__global__ __launch_bounds__(256, 2) void k_p2(const ushort* __restrict__ Zp,
                                               const ushort* __restrict__ Ep,
                                               const float* __restrict__ linv_in,
                                               float* __restrict__ P_sum) {
    __shared__ ushort Bu[2][16384];
    int t = threadIdx.x, lane = t & 63, w = t >> 6;
    int cg = blockIdx.x >> 2, rslice = blockIdx.x & 3;
    int wm = w >> 1, wn = w & 1;
    int n15 = lane & 15, quad = lane >> 4;
    int T = cg >> 1, cofs = (cg & 1) << 6;

    bf16x8 af[2][2][2];
#pragma unroll
    for (int ms = 0; ms < 2; ++ms) {
        int c = cofs + wm * 32 + ms * 16 + n15, cx = c & 7;
#pragma unroll
        for (int g = 0; g < 2; ++g)
#pragma unroll
            for (int kl = 0; kl < 2; ++kl)
                af[ms][g][kl] = *reinterpret_cast<const bf16x8*>(
                    &Ep[(((((T << 2) + g) << 10) + (c << 3) + ((kl * 4 + quad) ^ cx)) << 3)]);
    }

    float pacc[8];
#pragma unroll
    for (int s = 0; s < 8; ++s) pacc[s] = 0.f;

    {
        const ushort* gb = Zp + (((size_t)((rslice * 32) << 2)) << 13);
#pragma unroll
        for (int it = 0; it < 8; ++it) {
            int cpos = it * 256 + t;
            gld_lds16(gb + (cpos << 3), &Bu[0][cpos << 3]);
        }
    }
    int bufc = 0;
    for (int ch = 0; ch < 32; ++ch) {
        __syncthreads();
        if (ch < 31) {
            const ushort* gb = Zp + (((size_t)((rslice * 32 + ch + 1) << 2)) << 13);
            ushort* dst = Bu[bufc ^ 1];
#pragma unroll
            for (int it = 0; it < 8; ++it) {
                int cpos = it * 256 + t;
                gld_lds16(gb + (cpos << 3), &dst[cpos << 3]);
            }
        }
        const ushort* bsrc = Bu[bufc];
        f32x4 acc[2][4];
#pragma unroll
        for (int i = 0; i < 2; ++i)
#pragma unroll
            for (int j = 0; j < 4; ++j) acc[i][j] = (f32x4)2.0f;
#pragma unroll
        for (int g = 0; g < 2; ++g)
#pragma unroll
            for (int kl = 0; kl < 2; ++kl) {
                bf16x8 bfr[4];
#pragma unroll
                for (int ns = 0; ns < 4; ++ns) {
                    int r = wn * 64 + ns * 16 + n15;
                    int kx = (kl * 4 + quad) ^ (r & 7);
                    bfr[ns] = *reinterpret_cast<const bf16x8*>(
                        &bsrc[(((g << 10) + (r << 3) + kx) << 3)]);
                }
#pragma unroll
                for (int ms = 0; ms < 2; ++ms)
#pragma unroll
                    for (int ns = 0; ns < 4; ++ns)
                        acc[ms][ns] = MFMA16(af[ms][g][kl], bfr[ns], acc[ms][ns]);
            }
        int rbase = (rslice * 32 + ch) * 128 + wn * 64 + n15;
        float li[4];
#pragma unroll
        for (int ns = 0; ns < 4; ++ns) li[ns] = linv_in[rbase + ns * 16];
#pragma unroll
        for (int ms = 0; ms < 2; ++ms)
#pragma unroll
            for (int reg = 0; reg < 4; ++reg) {
                int s = ms * 4 + reg;
                float p = pacc[s];
#pragma unroll
                for (int ns = 0; ns < 4; ++ns)
                    p = fmaf(__expf(fmaf(acc[ms][ns][reg], 10.f, -20.f)), li[ns], p);
                pacc[s] = p;
            }
        bufc ^= 1;
    }
#pragma unroll
    for (int s = 0; s < 8; ++s) {
#pragma unroll
        for (int off = 1; off < 16; off <<= 1) pacc[s] += __shfl_xor(pacc[s], off);
    }
    if (n15 == 0) {
#pragma unroll
        for (int ms = 0; ms < 2; ++ms)
#pragma unroll
            for (int reg = 0; reg < 4; ++reg)
                atomicAdd(&P_sum[cg * 64 + wm * 32 + ms * 16 + quad * 4 + reg],
                          pacc[ms * 4 + reg]);
    }
}

// ---- gather z_q_st + commit-loss partial -----------------------------------
__global__ __launch_bounds__(256) void k_gather(const float* __restrict__ z,
                                                const float* __restrict__ W,
                                                const int* __restrict__ idx,
                                                float* __restrict__ out,
                                                float* __restrict__ mse) {
    int v = blockIdx.x * 256 + threadIdx.x;
    int row = v >> 5;
    int id = idx[row];
    float4 q = *reinterpret_cast<const float4*>(&W[(size_t)id * DIM + (v & 31) * 4]);
    float4 zz = *reinterpret_cast<const float4*>(&z[(size_t)v * 4]);
    float dx = q.x - zz.x, dy = q.y - zz.y, dz = q.z - zz.z, dw = q.w - zz.w;
    *reinterpret_cast<float4*>(&out[(size_t)v * 4]) = q;
    float e = dx * dx + dy * dy + dz * dz + dw * dw;
#pragma unroll
    for (int off = 1; off < 64; off <<= 1) e += __shfl_xor(e, off);
    __shared__ float red[4];
    int lane = threadIdx.x & 63, wv = threadIdx.x >> 6;
    if (lane == 0) red[wv] = e;
    __syncthreads();
    if (threadIdx.x == 0) atomicAdd(mse, red[0] + red[1] + red[2] + red[3]);
}

// ---- finalize scalars -------------------------------------------------------
__global__ __launch_bounds__(256) void k_finalize(const unsigned int* __restrict__ counts,
                                                  const float* __restrict__ P_sum,
                                                  const float* __restrict__ mse,
                                                  float* __restrict__ out) {
    int t = threadIdx.x;
    float s1 = 0.f, s2 = 0.f;
    for (int k = t; k < K_CODES; k += 256) {
        float em = (float)counts[k] * (1.0f / 16384.0f);
        s1 += em * logf(em + 1e-8f);
        float p = P_sum[k] * (1.0f / 16384.0f) + 1e-8f;
        s2 += p * logf(p);
    }
#pragma unroll
    for (int off = 1; off < 64; off <<= 1) {
        s1 += __shfl_xor(s1, off);
        s2 += __shfl_xor(s2, off);
    }
    __shared__ float r1[4], r2[4];
    int lane = t & 63, wv = t >> 6;
    if (lane == 0) { r1[wv] = s1; r2[wv] = s2; }
    __syncthreads();
    if (t == 0) {
        float S1 = r1[0] + r1[1] + r1[2] + r1[3];
        float S2 = r2[0] + r2[1] + r2[2] + r2[3];
        out[2097152] = 1.25f * mse[0] * (1.0f / 2097152.0f);
        out[2097153] = expf(-S1);
        out[2097154] = -S2;
    }
}

extern "C" void kernel_launch(void* const* d_in, const int* in_sizes, int n_in,
                              void* d_out, int out_size, void* d_ws, size_t ws_size,
                              hipStream_t stream) {
    (void)in_sizes; (void)n_in; (void)out_size; (void)ws_size;
    const float* z = (const float*)d_in[0];
    const float* W = (const float*)d_in[1];
    float* ws = (float*)d_ws;
    float* eN = ws + OFF_EN;
    float* zN = ws + OFF_ZN;
    ushort* Ep = (ushort*)(ws + OFF_EP);
    ushort* Zp = (ushort*)(ws + OFF_ZP);
    ushort* Zc = (ushort*)(ws + OFF_ZC);
    float4* part = (float4*)(ws + OFF_PART);
    float4* part2 = (float4*)(ws + OFF_PART2);
    float* linv = ws + OFF_LINV;
    int* idx = (int*)(ws + OFF_IDX);
    int* flaglistA = (int*)(ws + OFF_FLA);
    int* flaglistB = (int*)(ws + OFF_FLB);
    unsigned int* counts = (unsigned int*)(ws + OFF_CNT);
    float* P = ws + OFF_P;
    float* mse = ws + OFF_MSE;
    int* nfA = (int*)(ws + OFF_NFA);
    int* nfB = (int*)(ws + OFF_NFB);
    unsigned long long* refbuf = (unsigned long long*)(ws + OFF_REFBUF);
    float* out = (float*)d_out;

    hipMemsetAsync(ws + OFF_CNT, 0, MEMSET_BYTES, stream);
    k_prep<<<(N_ROWS + K_CODES) / 4, 256, 0, stream>>>(z, W, zN, eN, Zp, Ep);
    k_p1<<<1024, 256, 0, stream>>>(Zp, Ep, part);
    k_merge<<<N_ROWS / 256, 256, 0, stream>>>(part, linv, idx, counts, flaglistA, nfA);
    k_gather2<<<256, 256, 0, stream>>>(Zp, flaglistA, nfA, Zc);
    k_s2<<<1024, 256, 0, stream>>>(Zc, Ep, nfA, part2);
    k_merge2<<<32, 256, 0, stream>>>(part2, flaglistA, nfA, idx, counts, flaglistB, nfB);
    k_refine<<<4096, 256, 0, stream>>>(zN, eN, flaglistB, nfB, refbuf);
    k_fixidx<<<64, 256, 0, stream>>>(flaglistB, nfB, refbuf, idx, counts);
    k_p2<<<512, 256, 0, stream>>>(Zp, Ep, linv, P);
    k_gather<<<(N_ROWS * DIM / 4) / 256, 256, 0, stream>>>(z, W, idx, out, mse);
    k_finalize<<<1, 256, 0, stream>>>(counts, P, mse, out);
}

// Round 8
// 309.696 us; speedup vs baseline: 1.1940x; 1.0745x over previous
//
#include <hip/hip_runtime.h>
#include <hip/hip_bf16.h>
#include <math.h>

#define N_ROWS 16384
#define DIM 128
#define K_CODES 8192
#define EPS2 2e-3f            // hh-gap flag threshold (fp32-vs-hh delta rms ~2e-4)
#define EPSF 7e-5f            // split-gap flag threshold (split err ~1e-5)

// ---- workspace layout (float offsets) --------------------------------------
#define OFF_EN       0u          // eN fp32: 8192*128 = 1,048,576
#define OFF_ZN       1048576u    // zN fp32: 16384*128
#define OFF_EP       3145728u    // Ep bf16 4-group [hi|lo]: 64 tiles * 32768 us = 1,048,576 f
#define OFF_ZP       4194304u    // Zp bf16 4-group: 128 tiles * 32768 us = 2,097,152 f
#define OFF_ZC       6291456u    // Zc compact: 128 tiles(64r) * 16384 us = 1,048,576 f
#define OFF_PART     7340032u    // p1 partials: 4*16384 float4 = 262,144 f
#define OFF_PART2    7602176u    // s2 partials: 8*8192 float4 = 262,144 f
#define OFF_LINV     7864320u    // 16384
#define OFF_IDX      7880704u    // 16384 int
#define OFF_FLA      7897088u    // 16384 int
#define OFF_FLB      7913472u    // 16384 int
#define OFF_CNT      7929856u    // 8192 u32   <-- memset region starts here
#define OFF_P        7938048u    // 8192 f
#define OFF_MSE      7946240u    // 1
#define OFF_NFA      7946241u    // 1 int
#define OFF_NFB      7946242u    // 1 int (+1 pad)
#define OFF_REFBUF   7946244u    // 16384 u64 (byte off %8 == 0)
#define MEMSET_BYTES 196624u

typedef __bf16 bf16x8 __attribute__((ext_vector_type(8)));
typedef float  f32x4  __attribute__((ext_vector_type(4)));
#define MFMA16(a, b, c) __builtin_amdgcn_mfma_f32_16x16x32_bf16(a, b, c, 0, 0, 0)

__device__ __forceinline__ void gld_lds16(const ushort* g, ushort* l) {
    __builtin_amdgcn_global_load_lds(
        (const __attribute__((address_space(1))) unsigned int*)g,
        (__attribute__((address_space(3))) unsigned int*)l, 16, 0, 0);
}

__device__ __forceinline__ ushort f2bf(float x) {
    __hip_bfloat16 b = __float2bfloat16(x);
    return *reinterpret_cast<ushort*>(&b);
}
__device__ __forceinline__ float bf2f(ushort u) {
    __hip_bfloat16 b = *reinterpret_cast<__hip_bfloat16*>(&u);
    return __bfloat162float(b);
}

// 4-group tiled+swizzled store: tile T (128 rows), row r, k in [0,256):
// g = k>>6, chunk = r*8 + ((k>>3 & 7) ^ (r&7)); 16B chunks.
__device__ __forceinline__ void bf_store2(ushort* __restrict__ P, int T, int r,
                                          int rx, int k, ushort e0, ushort e1) {
    int g = k >> 6, kp = (k >> 3) & 7, j = k & 7;
    int off = (((((T << 2) + g) << 10) + (r << 3) + (kp ^ rx)) << 3) + j;
    *reinterpret_cast<ushort2*>(&P[off]) = make_ushort2(e0, e1);
}

// ---- fused prep: normalize z and W; write fp32 + 4-group [hi|lo] bf16 ------
__global__ __launch_bounds__(256) void k_prep(const float* __restrict__ z,
                                              const float* __restrict__ W,
                                              float* __restrict__ zN,
                                              float* __restrict__ eN,
                                              ushort* __restrict__ Zp,
                                              ushort* __restrict__ Ep) {
    int t = threadIdx.x, w = t >> 6, lane = t & 63;
    int row = blockIdx.x * 4 + w;
    const float* src; float* dstN; ushort* dstP;
    if (row < N_ROWS) { src = z; dstN = zN; dstP = Zp; }
    else { row -= N_ROWS; src = W; dstN = eN; dstP = Ep; }
    float2 v = *reinterpret_cast<const float2*>(&src[(size_t)row * DIM + lane * 2]);
    float ss = v.x * v.x + v.y * v.y;
#pragma unroll
    for (int off = 32; off; off >>= 1) ss += __shfl_xor(ss, off);
    float nrm = fmaxf(sqrtf(ss), 1e-12f);
    float a = v.x / nrm, b = v.y / nrm;
    *reinterpret_cast<float2*>(&dstN[(size_t)row * DIM + lane * 2]) = make_float2(a, b);
    ushort ha = f2bf(a), hb = f2bf(b);
    ushort la = f2bf(a - bf2f(ha)), lb = f2bf(b - bf2f(hb));
    int T = row >> 7, r = row & 127, rx = r & 7, d = lane * 2;
    bf_store2(dstP, T, r, rx, d, ha, hb);        // hi -> groups 0,1
    bf_store2(dstP, T, r, rx, 128 + d, la, lb);  // lo -> groups 2,3
}

// ---- phase 1: hh K=128 GEMM; A reg-stationary; B dbuf-LDS, 1 barrier/ch ----
// grid 1024: rg = b>>2 (256 groups of 64 rows), slice = b&3 (2048 codes).
__global__ __launch_bounds__(256, 2) void k_p1(const ushort* __restrict__ Zp,
                                               const ushort* __restrict__ Ep,
                                               float4* __restrict__ part) {
    __shared__ ushort Bu[2][16384];  // 2 x 32KB: 128 codes x 128 K (hi)
    int t = threadIdx.x, lane = t & 63, w = t >> 6;
    int rg = blockIdx.x >> 2, slice = blockIdx.x & 3;
    int wm = w >> 1, wn = w & 1;
    int n15 = lane & 15, quad = lane >> 4;
    int T = rg >> 1, rofs = (rg & 1) << 6;

    // stationary A: 8 frags (64 rows per block; 32 per wave)
    bf16x8 af[2][2][2];  // [ms][g][kl]
#pragma unroll
    for (int ms = 0; ms < 2; ++ms) {
        int r = rofs + wm * 32 + ms * 16 + n15, rx = r & 7;
#pragma unroll
        for (int g = 0; g < 2; ++g)
#pragma unroll
            for (int kl = 0; kl < 2; ++kl)
                af[ms][g][kl] = *reinterpret_cast<const bf16x8*>(
                    &Zp[(((((T << 2) + g) << 10) + (r << 3) + (((kl * 4 + quad)) ^ rx)) << 3)]);
    }

    float sm[8], s2v[8], sl[8];
    unsigned si[8];
#pragma unroll
    for (int s = 0; s < 8; ++s) { sm[s] = -1e30f; s2v[s] = -1e30f; sl[s] = 0.f; si[s] = 0u; }

    // pre-stage ch 0
    {
        const ushort* gb = Ep + (((size_t)(slice * 16) << 2) << 13);
#pragma unroll
        for (int it = 0; it < 8; ++it) {
            int cpos = it * 256 + t;
            gld_lds16(gb + (cpos << 3), &Bu[0][cpos << 3]);
        }
    }
    int bufc = 0;
    for (int ch = 0; ch < 16; ++ch) {
        __syncthreads();
        if (ch < 15) {
            const ushort* gb = Ep + (((size_t)((slice * 16 + ch + 1) << 2)) << 13);
            ushort* dst = Bu[bufc ^ 1];
#pragma unroll
            for (int it = 0; it < 8; ++it) {
                int cpos = it * 256 + t;
                gld_lds16(gb + (cpos << 3), &dst[cpos << 3]);
            }
        }
        const ushort* bsrc = Bu[bufc];
        f32x4 acc[2][4];
#pragma unroll
        for (int i = 0; i < 2; ++i)
#pragma unroll
            for (int j = 0; j < 4; ++j) acc[i][j] = (f32x4)2.0f;
#pragma unroll
        for (int g = 0; g < 2; ++g)
#pragma unroll
            for (int kl = 0; kl < 2; ++kl) {
                bf16x8 bfr[4];
#pragma unroll
                for (int ns = 0; ns < 4; ++ns) {
                    int c = wn * 64 + ns * 16 + n15;
                    int kx = (kl * 4 + quad) ^ (c & 7);
                    bfr[ns] = *reinterpret_cast<const bf16x8*>(
                        &bsrc[(((g << 10) + (c << 3) + kx) << 3)]);
                }
#pragma unroll
                for (int ms = 0; ms < 2; ++ms)
#pragma unroll
                    for (int ns = 0; ns < 4; ++ns)
                        acc[ms][ns] = MFMA16(af[ms][g][kl], bfr[ns], acc[ms][ns]);
            }
        // epilogue: sl + (m, m2, idx) on hh scores (biased +2)
        unsigned cbase = (unsigned)((slice * 16 + ch) * 128 + wn * 64 + n15);
#pragma unroll
        for (int ms = 0; ms < 2; ++ms)
#pragma unroll
            for (int reg = 0; reg < 4; ++reg) {
                int s = ms * 4 + reg;
                float m = sm[s], m2 = s2v[s], l = 0.f;
                unsigned idx = si[s];
#pragma unroll
                for (int ns = 0; ns < 4; ++ns) {
                    float v = acc[ms][ns][reg];
                    l += __expf(fmaf(v, 10.f, -20.f));
                    float lo = fminf(v, m);
                    m2 = fmaxf(m2, lo);
                    idx = (v > m) ? (cbase + ns * 16) : idx;
                    m = fmaxf(v, m);
                }
                sl[s] += l; sm[s] = m; s2v[s] = m2; si[s] = idx;
            }
        bufc ^= 1;
    }
    // cross-lane merge over 16-lane col group
#pragma unroll
    for (int ms = 0; ms < 2; ++ms)
#pragma unroll
        for (int reg = 0; reg < 4; ++reg) {
            int s = ms * 4 + reg;
            float m = sm[s], m2 = s2v[s], l = sl[s];
            unsigned idx = si[s];
#pragma unroll
            for (int off = 1; off < 16; off <<= 1) {
                float om  = __shfl_xor(m, off);
                float om2 = __shfl_xor(m2, off);
                float ol  = __shfl_xor(l, off);
                unsigned oi = (unsigned)__shfl_xor((int)idx, off);
                m2 = fmaxf(fmaxf(m2, om2), fminf(m, om));
                l += ol;
                bool take = (om > m) || (om == m && oi < idx);
                idx = take ? oi : idx;
                m = fmaxf(m, om);
            }
            if (n15 == 0) {
                int row = rg * 64 + wm * 32 + ms * 16 + quad * 4 + reg;
                part[slice * N_ROWS + row] = make_float4(m, l, __uint_as_float(idx), m2);
            }
        }
}

// ---- merge 4 slice-partials; counts; flag hh-gap < EPS2 --------------------
__global__ __launch_bounds__(256) void k_merge(const float4* __restrict__ part,
                                               float* __restrict__ linv_out,
                                               int* __restrict__ idx_out,
                                               unsigned int* __restrict__ counts,
                                               int* __restrict__ flaglistA,
                                               int* __restrict__ nfA) {
    int row = blockIdx.x * 256 + threadIdx.x;
    float m = -1e30f, m2 = -1e30f, l = 0.f;
    unsigned idx = 0u;
#pragma unroll
    for (int s = 0; s < 4; ++s) {
        float4 p = part[s * N_ROWS + row];
        float om = p.x, ol = p.y, om2 = p.w;
        unsigned oi = __float_as_uint(p.z);
        m2 = fmaxf(fmaxf(m2, om2), fminf(m, om));
        l += ol;
        bool take = (om > m) || (om == m && oi < idx);
        idx = take ? oi : idx;
        m = fmaxf(m, om);
    }
    linv_out[row] = 1.0f / l;
    idx_out[row] = (int)idx;
    atomicAdd(&counts[idx], 1u);
    if (m - m2 < EPS2) {
        int pos = atomicAdd(nfA, 1);
        if (pos < 8192) flaglistA[pos] = row;
    }
}

// ---- gather flagged rows into compact split-K tiles (64-row tiles) ---------
__global__ __launch_bounds__(256) void k_gather2(const ushort* __restrict__ Zp,
                                                 const int* __restrict__ flaglistA,
                                                 const int* __restrict__ nfA,
                                                 ushort* __restrict__ Zc) {
    int nf2 = *nfA; if (nf2 > 8192) nf2 = 8192;
    int total = nf2 * 32;  // 4 groups x 8 chunks per row
    const uint4* srcv = reinterpret_cast<const uint4*>(Zp);
    uint4* dstv = reinterpret_cast<uint4*>(Zc);
    for (int c = blockIdx.x * 256 + threadIdx.x; c < total; c += 65536) {
        int crow = c >> 5, g = (c >> 3) & 3, kp = c & 7;
        int row = flaglistA[crow];
        int Ts = row >> 7, rs = row & 127;
        int sidx = (((Ts << 2) + g) << 10) + (rs << 3) + (kp ^ (rs & 7));
        int Td = crow >> 6, rd = crow & 63;
        int didx = (((Td << 2) + g) << 9) + (rd << 3) + (kp ^ (rd & 7));
        dstv[didx] = srcv[sidx];
    }
}

// ---- stage 2: split-K re-argmax for flagged rows; B dbuf-LDS (p1-style) ----
// grid 1024: cg2 = b>>3 (compact rowgroup of 64, cap 8192 rows), csl = b&7.
// 32 stages of 16KB (8 ctiles x 4 groups); 1 barrier/stage; A reg-stationary.
__global__ __launch_bounds__(256, 2) void k_s2(const ushort* __restrict__ Zc,
                                               const ushort* __restrict__ Ep,
                                               const int* __restrict__ nfA,
                                               float4* __restrict__ part2) {
    __shared__ ushort Bu[2][8192];  // 2 x 16KB: 128 codes x 64 k (one group)
    int nf2 = *nfA; if (nf2 > 8192) nf2 = 8192;
    int cg2 = blockIdx.x >> 3, csl = blockIdx.x & 7;
    if (cg2 * 64 >= nf2) return;
    int t = threadIdx.x, lane = t & 63, w = t >> 6;
    int wm = w >> 1, wn = w & 1;
    int n15 = lane & 15, quad = lane >> 4;

    // stationary A: 16 frags [ms][gz 0..3][kl]
    bf16x8 af[2][4][2];
#pragma unroll
    for (int ms = 0; ms < 2; ++ms) {
        int r = wm * 32 + ms * 16 + n15, rx = r & 7;
#pragma unroll
        for (int gz = 0; gz < 4; ++gz)
#pragma unroll
            for (int kl = 0; kl < 2; ++kl)
                af[ms][gz][kl] = *reinterpret_cast<const bf16x8*>(
                    &Zc[(((((cg2 << 2) + gz) << 9) + (r << 3) + ((kl * 4 + quad) ^ rx)) << 3)]);
    }

    float sm[8], s2v[8];
    unsigned si[8];
#pragma unroll
    for (int s = 0; s < 8; ++s) { sm[s] = -1e30f; s2v[s] = -1e30f; si[s] = 0u; }

    // pre-stage stage 0: (ctile csl*8, group 0)
    {
        const ushort* gb = Ep + (((size_t)((csl * 8) << 2)) << 13);
#pragma unroll
        for (int it = 0; it < 4; ++it) {
            int cpos = it * 256 + t;
            gld_lds16(gb + (cpos << 3), &Bu[0][cpos << 3]);
        }
    }
    int bufc = 0;
    f32x4 acc[2][4];
#pragma unroll
    for (int i = 0; i < 2; ++i)
#pragma unroll
        for (int j = 0; j < 4; ++j) acc[i][j] = (f32x4)2.0f;

    for (int st = 0; st < 32; ++st) {
        __syncthreads();
        if (st < 31) {
            int nx = st + 1;
            const ushort* gb = Ep + (((size_t)(((csl * 8 + (nx >> 2)) << 2) + (nx & 3))) << 13);
            ushort* dst = Bu[bufc ^ 1];
#pragma unroll
            for (int it = 0; it < 4; ++it) {
                int cpos = it * 256 + t;
                gld_lds16(gb + (cpos << 3), &dst[cpos << 3]);
            }
        }
        const ushort* bsrc = Bu[bufc];
        int ge = st & 3;
        // products: ge0 -> A0,A2 (zh.eh, zl.eh lower K); ge1 -> A1,A3;
        //           ge2 -> A0 (zh.el lower K);           ge3 -> A1
        int a0 = ge & 1, a1 = (ge & 1) + 2;
        bool two = (ge < 2);
#pragma unroll
        for (int kl = 0; kl < 2; ++kl) {
            bf16x8 bfr[4];
#pragma unroll
            for (int ns = 0; ns < 4; ++ns) {
                int c = wn * 64 + ns * 16 + n15;
                int kx = (kl * 4 + quad) ^ (c & 7);
                bfr[ns] = *reinterpret_cast<const bf16x8*>(&bsrc[(((c << 3) + kx) << 3)]);
            }
#pragma unroll
            for (int ms = 0; ms < 2; ++ms)
#pragma unroll
                for (int ns = 0; ns < 4; ++ns)
                    acc[ms][ns] = MFMA16(af[ms][a0][kl], bfr[ns], acc[ms][ns]);
            if (two) {
#pragma unroll
                for (int ms = 0; ms < 2; ++ms)
#pragma unroll
                    for (int ns = 0; ns < 4; ++ns)
                        acc[ms][ns] = MFMA16(af[ms][a1][kl], bfr[ns], acc[ms][ns]);
            }
        }
        if (ge == 3) {
            int ch = st >> 2;
            unsigned cbase = (unsigned)((csl * 8 + ch) * 128 + wn * 64 + n15);
#pragma unroll
            for (int ms = 0; ms < 2; ++ms)
#pragma unroll
                for (int reg = 0; reg < 4; ++reg) {
                    int s = ms * 4 + reg;
                    float m = sm[s], m2 = s2v[s];
                    unsigned idx = si[s];
#pragma unroll
                    for (int ns = 0; ns < 4; ++ns) {
                        float v = acc[ms][ns][reg];
                        float lo = fminf(v, m);
                        m2 = fmaxf(m2, lo);
                        idx = (v > m) ? (cbase + ns * 16) : idx;
                        m = fmaxf(v, m);
                    }
                    sm[s] = m; s2v[s] = m2; si[s] = idx;
                }
#pragma unroll
            for (int i = 0; i < 2; ++i)
#pragma unroll
                for (int j = 0; j < 4; ++j) acc[i][j] = (f32x4)2.0f;
        }
        bufc ^= 1;
    }
#pragma unroll
    for (int ms = 0; ms < 2; ++ms)
#pragma unroll
        for (int reg = 0; reg < 4; ++reg) {
            int s = ms * 4 + reg;
            float m = sm[s], m2 = s2v[s];
            unsigned idx = si[s];
#pragma unroll
            for (int off = 1; off < 16; off <<= 1) {
                float om  = __shfl_xor(m, off);
                float om2 = __shfl_xor(m2, off);
                unsigned oi = (unsigned)__shfl_xor((int)idx, off);
                m2 = fmaxf(fmaxf(m2, om2), fminf(m, om));
                bool take = (om > m) || (om == m && oi < idx);
                idx = take ? oi : idx;
                m = fmaxf(m, om);
            }
            if (n15 == 0) {
                int crow = cg2 * 64 + wm * 32 + ms * 16 + quad * 4 + reg;
                part2[csl * 8192 + crow] = make_float4(m, 0.f, __uint_as_float(idx), m2);
            }
        }
}

// ---- merge stage-2 slices; fix idx/counts; flag split-gap < EPSF -----------
__global__ __launch_bounds__(256) void k_merge2(const float4* __restrict__ part2,
                                                const int* __restrict__ flaglistA,
                                                const int* __restrict__ nfA,
                                                int* __restrict__ idx_arr,
                                                unsigned int* __restrict__ counts,
                                                int* __restrict__ flaglistB,
                                                int* __restrict__ nfB) {
    int i = blockIdx.x * 256 + threadIdx.x;
    int nf2 = *nfA; if (nf2 > 8192) nf2 = 8192;
    if (i >= nf2) return;
    int row = flaglistA[i];
    float m = -1e30f, m2 = -1e30f;
    unsigned idx = 0u;
#pragma unroll
    for (int s = 0; s < 8; ++s) {
        float4 p = part2[s * 8192 + i];
        float om = p.x, om2 = p.w;
        unsigned oi = __float_as_uint(p.z);
        m2 = fmaxf(fmaxf(m2, om2), fminf(m, om));
        bool take = (om > m) || (om == m && oi < idx);
        idx = take ? oi : idx;
        m = fmaxf(m, om);
    }
    int newi = (int)idx, oldi = idx_arr[row];
    if (newi != oldi) {
        idx_arr[row] = newi;
        atomicAdd(&counts[oldi], 0xFFFFFFFFu);
        atomicAdd(&counts[newi], 1u);
    }
    if (m - m2 < EPSF) {
        int pos = atomicAdd(nfB, 1);
        if (pos < N_ROWS) flaglistB[pos] = row;
    }
}

// ---- fp64 exact re-argmax for stage-3 rows ---------------------------------
__global__ __launch_bounds__(256) void k_refine(const float* __restrict__ zN,
                                                const float* __restrict__ eN,
                                                const int* __restrict__ flaglistB,
                                                const int* __restrict__ nfB,
                                                unsigned long long* __restrict__ refbuf) {
    int nf = *nfB;
    if (nf > N_ROWS) nf = N_ROWS;
    int csl = blockIdx.x & 7;
    int t = threadIdx.x;
    __shared__ float zl[DIM];
    for (int fi = blockIdx.x >> 3; fi < nf; fi += 512) {
        int row = flaglistB[fi];
        __syncthreads();
        if (t < DIM) zl[t] = zN[(size_t)row * DIM + t];
        __syncthreads();
        double best = -1e300;
        int bc = 0x7FFFFFFF;
#pragma unroll
        for (int j = 0; j < 4; ++j) {
            int c = csl * 1024 + j * 256 + t;
            const float* e = &eN[(size_t)c * DIM];
            double s = 0.0;
#pragma unroll 8
            for (int d = 0; d < DIM; ++d) s += (double)zl[d] * (double)e[d];
            if (s > best) { best = s; bc = c; }
        }
#pragma unroll
        for (int off = 1; off < 64; off <<= 1) {
            double ob = __shfl_xor(best, off);
            int oc = __shfl_xor(bc, off);
            if (ob > best || (ob == best && oc < bc)) { best = ob; bc = oc; }
        }
        if ((t & 63) == 0) {
            unsigned long long u = (unsigned long long)__double_as_longlong(best);
            u = (u & 0x8000000000000000ull) ? ~u : (u | 0x8000000000000000ull);
            unsigned long long key = (u & ~0x1FFFull) | (unsigned long long)(8191 - bc);
            atomicMax(&refbuf[row], key);
        }
    }
}

__global__ __launch_bounds__(256) void k_fixidx(const int* __restrict__ flaglistB,
                                                const int* __restrict__ nfB,
                                                const unsigned long long* __restrict__ refbuf,
                                                int* __restrict__ idx,
                                                unsigned int* __restrict__ counts) {
    int i = blockIdx.x * 256 + threadIdx.x;
    int nf = *nfB;
    if (nf > N_ROWS) nf = N_ROWS;
    if (i < nf) {
        int row = flaglistB[i];
        int newi = 8191 - (int)(refbuf[row] & 0x1FFFull);
        int oldi = idx[row];
        if (newi != oldi) {
            idx[row] = newi;
            atomicAdd(&counts[oldi], 0xFFFFFFFFu);
            atomicAdd(&counts[newi], 1u);
        }
    }
}

// ---- phase 2: mirrored p1 — codes reg-stationary, rows dbuf-LDS ------------
// grid 512: cg = b>>2 (128 groups of 64 codes), rslice = b&3 (4096 rows).
__global__ __launch_bounds__(256, 2) void k_p2(const ushort* __restrict__ Zp,
                                               const ushort* __restrict__ Ep,
                                               const float* __restrict__ linv_in,
                                               float* __restrict__ P_sum) {
    __shared__ ushort Bu[2][16384];
    int t = threadIdx.x, lane = t & 63, w = t >> 6;
    int cg = blockIdx.x >> 2, rslice = blockIdx.x & 3;
    int wm = w >> 1, wn = w & 1;
    int n15 = lane & 15, quad = lane >> 4;
    int T = cg >> 1, cofs = (cg & 1) << 6;

    bf16x8 af[2][2][2];
#pragma unroll
    for (int ms = 0; ms < 2; ++ms) {
        int c = cofs + wm * 32 + ms * 16 + n15, cx = c & 7;
#pragma unroll
        for (int g = 0; g < 2; ++g)
#pragma unroll
            for (int kl = 0; kl < 2; ++kl)
                af[ms][g][kl] = *reinterpret_cast<const bf16x8*>(
                    &Ep[(((((T << 2) + g) << 10) + (c << 3) + ((kl * 4 + quad) ^ cx)) << 3)]);
    }

    float pacc[8];
#pragma unroll
    for (int s = 0; s < 8; ++s) pacc[s] = 0.f;

    {
        const ushort* gb = Zp + (((size_t)((rslice * 32) << 2)) << 13);
#pragma unroll
        for (int it = 0; it < 8; ++it) {
            int cpos = it * 256 + t;
            gld_lds16(gb + (cpos << 3), &Bu[0][cpos << 3]);
        }
    }
    int bufc = 0;
    for (int ch = 0; ch < 32; ++ch) {
        __syncthreads();
        if (ch < 31) {
            const ushort* gb = Zp + (((size_t)((rslice * 32 + ch + 1) << 2)) << 13);
            ushort* dst = Bu[bufc ^ 1];
#pragma unroll
            for (int it = 0; it < 8; ++it) {
                int cpos = it * 256 + t;
                gld_lds16(gb + (cpos << 3), &dst[cpos << 3]);
            }
        }
        const ushort* bsrc = Bu[bufc];
        f32x4 acc[2][4];
#pragma unroll
        for (int i = 0; i < 2; ++i)
#pragma unroll
            for (int j = 0; j < 4; ++j) acc[i][j] = (f32x4)2.0f;
#pragma unroll
        for (int g = 0; g < 2; ++g)
#pragma unroll
            for (int kl = 0; kl < 2; ++kl) {
                bf16x8 bfr[4];
#pragma unroll
                for (int ns = 0; ns < 4; ++ns) {
                    int r = wn * 64 + ns * 16 + n15;
                    int kx = (kl * 4 + quad) ^ (r & 7);
                    bfr[ns] = *reinterpret_cast<const bf16x8*>(
                        &bsrc[(((g << 10) + (r << 3) + kx) << 3)]);
                }
#pragma unroll
                for (int ms = 0; ms < 2; ++ms)
#pragma unroll
                    for (int ns = 0; ns < 4; ++ns)
                        acc[ms][ns] = MFMA16(af[ms][g][kl], bfr[ns], acc[ms][ns]);
            }
        int rbase = (rslice * 32 + ch) * 128 + wn * 64 + n15;
        float li[4];
#pragma unroll
        for (int ns = 0; ns < 4; ++ns) li[ns] = linv_in[rbase + ns * 16];
#pragma unroll
        for (int ms = 0; ms < 2; ++ms)
#pragma unroll
            for (int reg = 0; reg < 4; ++reg) {
                int s = ms * 4 + reg;
                float p = pacc[s];
#pragma unroll
                for (int ns = 0; ns < 4; ++ns)
                    p = fmaf(__expf(fmaf(acc[ms][ns][reg], 10.f, -20.f)), li[ns], p);
                pacc[s] = p;
            }
        bufc ^= 1;
    }
#pragma unroll
    for (int s = 0; s < 8; ++s) {
#pragma unroll
        for (int off = 1; off < 16; off <<= 1) pacc[s] += __shfl_xor(pacc[s], off);
    }
    if (n15 == 0) {
#pragma unroll
        for (int ms = 0; ms < 2; ++ms)
#pragma unroll
            for (int reg = 0; reg < 4; ++reg)
                atomicAdd(&P_sum[cg * 64 + wm * 32 + ms * 16 + quad * 4 + reg],
                          pacc[ms * 4 + reg]);
    }
}

// ---- gather z_q_st + commit-loss partial -----------------------------------
__global__ __launch_bounds__(256) void k_gather(const float* __restrict__ z,
                                                const float* __restrict__ W,
                                                const int* __restrict__ idx,
                                                float* __restrict__ out,
                                                float* __restrict__ mse) {
    int v = blockIdx.x * 256 + threadIdx.x;
    int row = v >> 5;
    int id = idx[row];
    float4 q = *reinterpret_cast<const float4*>(&W[(size_t)id * DIM + (v & 31) * 4]);
    float4 zz = *reinterpret_cast<const float4*>(&z[(size_t)v * 4]);
    float dx = q.x - zz.x, dy = q.y - zz.y, dz = q.z - zz.z, dw = q.w - zz.w;
    *reinterpret_cast<float4*>(&out[(size_t)v * 4]) = q;
    float e = dx * dx + dy * dy + dz * dz + dw * dw;
#pragma unroll
    for (int off = 1; off < 64; off <<= 1) e += __shfl_xor(e, off);
    __shared__ float red[4];
    int lane = threadIdx.x & 63, wv = threadIdx.x >> 6;
    if (lane == 0) red[wv] = e;
    __syncthreads();
    if (threadIdx.x == 0) atomicAdd(mse, red[0] + red[1] + red[2] + red[3]);
}

// ---- finalize scalars -------------------------------------------------------
__global__ __launch_bounds__(256) void k_finalize(const unsigned int* __restrict__ counts,
                                                  const float* __restrict__ P_sum,
                                                  const float* __restrict__ mse,
                                                  float* __restrict__ out) {
    int t = threadIdx.x;
    float s1 = 0.f, s2 = 0.f;
    for (int k = t; k < K_CODES; k += 256) {
        float em = (float)counts[k] * (1.0f / 16384.0f);
        s1 += em * logf(em + 1e-8f);
        float p = P_sum[k] * (1.0f / 16384.0f) + 1e-8f;
        s2 += p * logf(p);
    }
#pragma unroll
    for (int off = 1; off < 64; off <<= 1) {
        s1 += __shfl_xor(s1, off);
        s2 += __shfl_xor(s2, off);
    }
    __shared__ float r1[4], r2[4];
    int lane = t & 63, wv = t >> 6;
    if (lane == 0) { r1[wv] = s1; r2[wv] = s2; }
    __syncthreads();
    if (t == 0) {
        float S1 = r1[0] + r1[1] + r1[2] + r1[3];
        float S2 = r2[0] + r2[1] + r2[2] + r2[3];
        out[2097152] = 1.25f * mse[0] * (1.0f / 2097152.0f);
        out[2097153] = expf(-S1);
        out[2097154] = -S2;
    }
}

extern "C" void kernel_launch(void* const* d_in, const int* in_sizes, int n_in,
                              void* d_out, int out_size, void* d_ws, size_t ws_size,
                              hipStream_t stream) {
    (void)in_sizes; (void)n_in; (void)out_size; (void)ws_size;
    const float* z = (const float*)d_in[0];
    const float* W = (const float*)d_in[1];
    float* ws = (float*)d_ws;
    float* eN = ws + OFF_EN;
    float* zN = ws + OFF_ZN;
    ushort* Ep = (ushort*)(ws + OFF_EP);
    ushort* Zp = (ushort*)(ws + OFF_ZP);
    ushort* Zc = (ushort*)(ws + OFF_ZC);
    float4* part = (float4*)(ws + OFF_PART);
    float4* part2 = (float4*)(ws + OFF_PART2);
    float* linv = ws + OFF_LINV;
    int* idx = (int*)(ws + OFF_IDX);
    int* flaglistA = (int*)(ws + OFF_FLA);
    int* flaglistB = (int*)(ws + OFF_FLB);
    unsigned int* counts = (unsigned int*)(ws + OFF_CNT);
    float* P = ws + OFF_P;
    float* mse = ws + OFF_MSE;
    int* nfA = (int*)(ws + OFF_NFA);
    int* nfB = (int*)(ws + OFF_NFB);
    unsigned long long* refbuf = (unsigned long long*)(ws + OFF_REFBUF);
    float* out = (float*)d_out;

    hipMemsetAsync(ws + OFF_CNT, 0, MEMSET_BYTES, stream);
    k_prep<<<(N_ROWS + K_CODES) / 4, 256, 0, stream>>>(z, W, zN, eN, Zp, Ep);
    k_p1<<<1024, 256, 0, stream>>>(Zp, Ep, part);
    k_merge<<<N_ROWS / 256, 256, 0, stream>>>(part, linv, idx, counts, flaglistA, nfA);
    k_gather2<<<256, 256, 0, stream>>>(Zp, flaglistA, nfA, Zc);
    k_s2<<<1024, 256, 0, stream>>>(Zc, Ep, nfA, part2);
    k_merge2<<<32, 256, 0, stream>>>(part2, flaglistA, nfA, idx, counts, flaglistB, nfB);
    k_refine<<<4096, 256, 0, stream>>>(zN, eN, flaglistB, nfB, refbuf);
    k_fixidx<<<64, 256, 0, stream>>>(flaglistB, nfB, refbuf, idx, counts);
    k_p2<<<512, 256, 0, stream>>>(Zp, Ep, linv, P);
    k_gather<<<(N_ROWS * DIM / 4) / 256, 256, 0, stream>>>(z, W, idx, out, mse);
    k_finalize<<<1, 256, 0, stream>>>(counts, P, mse, out);
}